// Round 2
// baseline (227.170 us; speedup 1.0000x reference)
//
#include <hip/hip_runtime.h>
#include <hip/hip_bf16.h>

// SConv: x(8,64,128,128) f32, Coefficient(9,9), W(128,64,3,3), b(128)
// out[b,co,h,w] = sum_{c,t} z[b,c,h,w][t] * W[co,c,t] + b[co]
// z = [sorted8(y[noncenter])[0:4], center, sorted8[4:8]],
// y_i = sum_j Coefficient[i,j] * patch_j (3x3 neighborhood, zero pad 1).
//
// Round 9 (vs round 8, 95 us: LDS-read-bound in Phase B — 8 waves each
// re-read the full 37 KB Z panel = 1.18 MB/CU-round at ~100 B/cyc ~= the
// whole round; bank conflicts tripled from SROW=584's weak b128 mapping):
//  - Phase B retile: wave = (m-tile, n-PAIR) instead of (2 m-tiles, 1
//    n-tile). Per ks: 1 A ds_read_b128 + 2 B global loads + 2 MFMAs.
//    Halves Phase-B LDS read traffic (294->147 KB/block); doubles Wb L2
//    traffic (L2 has ~3x headroom).
//  - SROW 584 -> 600: byte stride 1200, S/4 = 12 mod 32 (odd multiple of
//    4) -> each 8-lane beat of ds_read_b128 covers all 32 banks
//    (conflict-free stride). LDS 38400 B, still 4 blocks/CU.
// MFMA 16x16x32 bf16, verified layouts (m89/m91/m97) unchanged.

#define B_   8
#define C_   64
#define H_   128
#define W_   128
#define CO_  128
#define K_   576    // C_*9
#define MT   32     // sites per block (2h x 16w)
#define SROW 600    // LDS row stride in elements (1200 B, 16B aligned)

typedef __attribute__((ext_vector_type(8))) short  short8;
typedef __attribute__((ext_vector_type(8))) __bf16 bf16x8;
typedef __attribute__((ext_vector_type(4))) float  f32x4;
typedef __attribute__((ext_vector_type(2))) float  f32x2;

__device__ __forceinline__ void cswap2(f32x2 &a, f32x2 &b) {
    f32x2 lo = __builtin_elementwise_min(a, b);
    f32x2 hi = __builtin_elementwise_max(a, b);
    a = lo; b = hi;
}

__device__ __forceinline__ ushort f2bf(float f) {
    union { float f; unsigned u; } v; v.f = f;
    unsigned r = v.u + 0x7fffu + ((v.u >> 16) & 1u);  // RNE
    return (ushort)(r >> 16);
}

__device__ __forceinline__ unsigned pack2bf(float lo, float hi) {
    union { __hip_bfloat162 h; unsigned u; } cv;
    cv.h = __float22bfloat162_rn(make_float2(lo, hi));  // x->low word
    return cv.u;
}

// W[co][c][t] f32 -> bf16 (layout already B^T = [n=co][k=c*9+t])
__global__ __launch_bounds__(256) void conv_W_bf16(const float* __restrict__ Wg,
                                                   ushort* __restrict__ Wb) {
    int i = blockIdx.x * 256 + threadIdx.x;
    if (i < CO_ * K_) Wb[i] = f2bf(Wg[i]);
}

__global__ __launch_bounds__(512, 8) void sconv_mfma(
    const float* __restrict__ x,
    const float* __restrict__ Coef,
    const ushort* __restrict__ Wb,     // bf16 bits [co][k]
    const float* __restrict__ bias,
    float* __restrict__ out)
{
    __shared__ __align__(16) ushort Zl[MT * SROW];   // 38400 B

    const int tid = threadIdx.x;
    const int bx  = blockIdx.x;
    const int wq  = bx & 7;            // which 16-wide slice of the row
    const int hp  = (bx >> 3) & 63;    // h pair index
    const int b   = bx >> 9;
    const int w0  = wq * 16;
    const int h0  = hp * 2;

    // ---- Phase A: z for 64 c x (2h x 16w) sites; 2w x 2h per thread ----
    {
        const int c  = tid >> 3;               // 64 channels
        const int pw = tid & 7;                // 8 w-pairs
        const int w  = w0 + pw * 2;
        const float* xb = x + ((size_t)(b * C_ + c)) * (H_ * W_);

        // 4 rows x 4 cols of padded input (covers 2x2 sites' 3x3 patches)
        float r[4][4];
        const bool interior = (h0 >= 2) && (h0 <= 124) && (w0 >= 16) && (w0 <= 96);
        if (interior) {                        // block-uniform: scalar branch
            const float* bp = xb + (h0 - 1) * W_ + (w - 1);
            #pragma unroll
            for (int dy = 0; dy < 4; ++dy) {
                float4 v; __builtin_memcpy(&v, bp + dy * W_, 16);  // dwordx4 @4B align
                r[dy][0] = v.x; r[dy][1] = v.y; r[dy][2] = v.z; r[dy][3] = v.w;
            }
        } else {
            // branch-free clamped loads + selects (no per-lane divergence)
            const int wm = w - 1;
            const int wc = min(max(wm, 0), W_ - 4);
            const int s  = wm - wc;            // -1 (left pad), 0, +1 (right pad)
            #pragma unroll
            for (int dy = 0; dy < 4; ++dy) {
                const int hy  = h0 + dy - 1;
                const bool hok = (unsigned)hy < (unsigned)H_;
                const int hc  = min(max(hy, 0), H_ - 1);
                float4 v; __builtin_memcpy(&v, xb + hc * W_ + wc, 16);
                const float rr0 = (s < 0) ? 0.f : ((s > 0) ? v.y : v.x);
                const float rr1 = (s < 0) ? v.x : ((s > 0) ? v.z : v.y);
                const float rr2 = (s < 0) ? v.y : ((s > 0) ? v.w : v.z);
                const float rr3 = (s < 0) ? v.z : ((s > 0) ? 0.f : v.w);
                r[dy][0] = hok ? rr0 : 0.f;
                r[dy][1] = hok ? rr1 : 0.f;
                r[dy][2] = hok ? rr2 : 0.f;
                r[dy][3] = hok ? rr3 : 0.f;
            }
        }

        const int k0 = c * 9;
        #pragma unroll
        for (int hl = 0; hl < 2; ++hl) {       // two h-sites share 2 of 3 rows
            f32x2 p2[9];
            #pragma unroll
            for (int dy = 0; dy < 3; ++dy)
                #pragma unroll
                for (int dx = 0; dx < 3; ++dx)
                    p2[dy * 3 + dx] = (f32x2){ r[hl + dy][dx], r[hl + dy][dx + 1] };

            // y_i for i in {0,1,2,3,5,6,7,8}; Coef via uniform (scalar) loads
            f32x2 v2[8];
            #pragma unroll
            for (int ii = 0; ii < 8; ++ii) {
                const int i = ii + (ii >> 2);
                f32x2 acc = p2[0] * Coef[i * 9];
                #pragma unroll
                for (int j = 1; j < 9; ++j) acc += p2[j] * Coef[i * 9 + j];
                v2[ii] = acc;
            }

            // Batcher odd-even mergesort, 8 elems, ascending (19 comparators)
            cswap2(v2[0],v2[1]); cswap2(v2[2],v2[3]); cswap2(v2[4],v2[5]); cswap2(v2[6],v2[7]);
            cswap2(v2[0],v2[2]); cswap2(v2[1],v2[3]); cswap2(v2[4],v2[6]); cswap2(v2[5],v2[7]);
            cswap2(v2[1],v2[2]); cswap2(v2[5],v2[6]);
            cswap2(v2[0],v2[4]); cswap2(v2[1],v2[5]); cswap2(v2[2],v2[6]); cswap2(v2[3],v2[7]);
            cswap2(v2[2],v2[4]); cswap2(v2[3],v2[5]);
            cswap2(v2[1],v2[2]); cswap2(v2[3],v2[4]); cswap2(v2[5],v2[6]);

            f32x2 z2[9] = { v2[0], v2[1], v2[2], v2[3], p2[4],
                            v2[4], v2[5], v2[6], v2[7] };

            // Z rows m = hl*16 + (pw*2, pw*2+1)
            ushort* zr0 = &Zl[(hl * 16 + pw * 2    ) * SROW];
            ushort* zr1 = &Zl[(hl * 16 + pw * 2 + 1) * SROW];
            if ((k0 & 1) == 0) {                    // pairs k0.., single at k0+8
                #pragma unroll
                for (int q = 0; q < 4; ++q) {
                    *(unsigned*)&zr0[k0 + 2*q] = pack2bf(z2[2*q][0], z2[2*q+1][0]);
                    *(unsigned*)&zr1[k0 + 2*q] = pack2bf(z2[2*q][1], z2[2*q+1][1]);
                }
                zr0[k0 + 8] = f2bf(z2[8][0]);
                zr1[k0 + 8] = f2bf(z2[8][1]);
            } else {                                // single at k0, pairs k0+1..
                zr0[k0] = f2bf(z2[0][0]);
                zr1[k0] = f2bf(z2[0][1]);
                #pragma unroll
                for (int q = 0; q < 4; ++q) {
                    *(unsigned*)&zr0[k0 + 1 + 2*q] = pack2bf(z2[1+2*q][0], z2[2+2*q][0]);
                    *(unsigned*)&zr1[k0 + 1 + 2*q] = pack2bf(z2[1+2*q][1], z2[2+2*q][1]);
                }
            }
        }
    }
    __syncthreads();

    // ---- Phase B: MFMA GEMM  out[m, n=co] = sum_k Z[m,k] * W^T[n,k] ----
    // Wave tiling: wave = (m-tile mt = wave>>2, n-pair np = wave&3).
    // Per ks: ONE A ds_read_b128 feeds TWO MFMAs (different B) -> halves
    // LDS read traffic vs (2m x 1n) tiling.
    const int wave = tid >> 6;
    const int lane = tid & 63;
    const int quad = lane >> 4;
    const int l16  = lane & 15;
    const int mt   = wave >> 2;        // 0: h0 row, 1: h0+1 row
    const int np   = wave & 3;         // co tiles 2np, 2np+1

    const ushort* arow  = &Zl[(mt * 16 + l16) * SROW];
    const ushort* brow0 = Wb + (size_t)(np * 32 + l16) * K_ + quad * 8;
    const ushort* brow1 = brow0 + 16 * K_;

    f32x4 acc0 = {0.f,0.f,0.f,0.f}, acc1 = acc0;

    #pragma unroll
    for (int ks = 0; ks < 18; ++ks) {
        const int ko = ks * 32 + quad * 8;     // this lane's k-chunk base
        bf16x8 a  = *(const bf16x8*)(arow + ko);   // single ds_read_b128
        bf16x8 b0 = __builtin_bit_cast(bf16x8, *(const short8*)(brow0 + ks * 32));
        bf16x8 b1 = __builtin_bit_cast(bf16x8, *(const short8*)(brow1 + ks * 32));
        acc0 = __builtin_amdgcn_mfma_f32_16x16x32_bf16(a, b0, acc0, 0, 0, 0);
        acc1 = __builtin_amdgcn_mfma_f32_16x16x32_bf16(a, b1, acc1, 0, 0, 0);
    }

    // ---- Epilogue: C/D row=(quad*4+reg) -> w-local, col=l16 -> co-local ----
    const int co0 = np * 32 + l16;             // acc0 co; acc1 = co0+16
    const int h   = h0 + mt;
    const float bv0 = bias[co0];
    const float bv1 = bias[co0 + 16];
    float* o0 = out + (((size_t)(b * CO_ + co0)) * H_ + h) * W_ + w0 + quad * 4;
    float* o1 = o0 + (size_t)16 * H_ * W_;     // co0+16, same (h,w)
    *(float4*)o0 = make_float4(acc0.x + bv0, acc0.y + bv0, acc0.z + bv0, acc0.w + bv0);
    *(float4*)o1 = make_float4(acc1.x + bv1, acc1.y + bv1, acc1.z + bv1, acc1.w + bv1);
}

// ---- fp32 fallback (round-1 kernel, direct W layout) if ws is too small ----
#define WT 16
__device__ __forceinline__ void cswap(float &a, float &b) {
    float lo = fminf(a, b);
    float hi = fmaxf(a, b);
    a = lo; b = hi;
}
__global__ __launch_bounds__(256) void sconv_fp32(
    const float* __restrict__ x, const float* __restrict__ Coef,
    const float* __restrict__ Wg, const float* __restrict__ bias,
    float* __restrict__ out)
{
    __shared__ float Cf[81];
    __shared__ float Zl[C_ * 9 * WT];
    const int tid = threadIdx.x;
    const int bx  = blockIdx.x;
    const int wt  = bx & 7;
    const int h   = (bx >> 3) & 127;
    const int b   = bx >> 10;
    const int w0  = wt * WT;
    if (tid < 81) Cf[tid] = Coef[tid];
    __syncthreads();
    for (int task = tid; task < C_ * WT; task += 256) {
        const int c = task >> 4, wl = task & 15, w = w0 + wl;
        const float* xb = x + (b * C_ + c) * H_ * W_;
        float p[9];
        #pragma unroll
        for (int dy = 0; dy < 3; ++dy) {
            const int hy = h + dy - 1; const bool hin = (unsigned)hy < (unsigned)H_;
            #pragma unroll
            for (int dx = 0; dx < 3; ++dx) {
                const int wx = w + dx - 1; const bool win = (unsigned)wx < (unsigned)W_;
                p[dy * 3 + dx] = (hin && win) ? xb[hy * W_ + wx] : 0.0f;
            }
        }
        float v[8];
        #pragma unroll
        for (int ii = 0; ii < 8; ++ii) {
            const int i = ii + (ii >> 2);
            float acc = 0.0f;
            #pragma unroll
            for (int j = 0; j < 9; ++j) acc = fmaf(Cf[i * 9 + j], p[j], acc);
            v[ii] = acc;
        }
        cswap(v[0], v[1]); cswap(v[2], v[3]); cswap(v[4], v[5]); cswap(v[6], v[7]);
        cswap(v[0], v[2]); cswap(v[1], v[3]); cswap(v[4], v[6]); cswap(v[5], v[7]);
        cswap(v[1], v[2]); cswap(v[5], v[6]);
        cswap(v[0], v[4]); cswap(v[1], v[5]); cswap(v[2], v[6]); cswap(v[3], v[7]);
        cswap(v[2], v[4]); cswap(v[3], v[5]);
        cswap(v[1], v[2]); cswap(v[3], v[4]); cswap(v[5], v[6]);
        const int base = c * 9 * WT + wl;
        Zl[base + 0*WT]=v[0]; Zl[base + 1*WT]=v[1]; Zl[base + 2*WT]=v[2]; Zl[base + 3*WT]=v[3];
        Zl[base + 4*WT]=p[4];
        Zl[base + 5*WT]=v[4]; Zl[base + 6*WT]=v[5]; Zl[base + 7*WT]=v[6]; Zl[base + 8*WT]=v[7];
    }
    __syncthreads();
    const int co = tid >> 1, w0l = (tid & 1) * 8;
    float acc[8];
    #pragma unroll
    for (int i = 0; i < 8; ++i) acc[i] = 0.0f;
    for (int c = 0; c < C_; ++c) {
        #pragma unroll
        for (int t = 0; t < 9; ++t) {
            const float wv = Wg[(co * C_ + c) * 9 + t];
            const float* zp = &Zl[(c * 9 + t) * WT + w0l];
            const float4 za = *(const float4*)zp;
            const float4 zb = *(const float4*)(zp + 4);
            acc[0]=fmaf(za.x,wv,acc[0]); acc[1]=fmaf(za.y,wv,acc[1]);
            acc[2]=fmaf(za.z,wv,acc[2]); acc[3]=fmaf(za.w,wv,acc[3]);
            acc[4]=fmaf(zb.x,wv,acc[4]); acc[5]=fmaf(zb.y,wv,acc[5]);
            acc[6]=fmaf(zb.z,wv,acc[6]); acc[7]=fmaf(zb.w,wv,acc[7]);
        }
    }
    const float bv = bias[co];
    float* op = out + ((b * CO_ + co) * H_ + h) * W_ + w0 + w0l;
    *(float4*)(op)     = make_float4(acc[0]+bv, acc[1]+bv, acc[2]+bv, acc[3]+bv);
    *(float4*)(op + 4) = make_float4(acc[4]+bv, acc[5]+bv, acc[6]+bv, acc[7]+bv);
}

extern "C" void kernel_launch(void* const* d_in, const int* in_sizes, int n_in,
                              void* d_out, int out_size, void* d_ws, size_t ws_size,
                              hipStream_t stream) {
    const float* x    = (const float*)d_in[0];
    const float* Coef = (const float*)d_in[1];
    const float* Wg   = (const float*)d_in[2];
    const float* bias = (const float*)d_in[3];
    float* out = (float*)d_out;

    const size_t need = (size_t)CO_ * K_ * sizeof(ushort);   // 147456 B
    if (ws_size >= need) {
        ushort* Wb = (ushort*)d_ws;
        conv_W_bf16<<<(CO_ * K_ + 255) / 256, 256, 0, stream>>>(Wg, Wb);
        sconv_mfma<<<B_ * (H_ / 2) * (W_ / 16), 512, 0, stream>>>(x, Coef, Wb, bias, out);
    } else {
        sconv_fp32<<<B_ * H_ * 8, 256, 0, stream>>>(x, Coef, Wg, bias, out);
    }
}

// Round 3
// 139.126 us; speedup vs baseline: 1.6328x; 1.6328x over previous
//
#include <hip/hip_runtime.h>
#include <hip/hip_bf16.h>

// SConv: x(8,64,128,128) f32, Coefficient(9,9), W(128,64,3,3), b(128)
// out[b,co,h,w] = sum_{c,t} z[b,c,h,w][t] * W[co,c,t] + b[co]
// z = [sorted8(y[noncenter])[0:4], center, sorted8[4:8]],
// y_i = sum_j Coefficient[i,j] * patch_j (3x3 neighborhood, zero pad 1).
//
// Round 10 (post-mortem R8/R9: NOT pipe-bound — dependency-latency-bound.
// VGPR_Count 24-32 under __launch_bounds__(512,8) left zero room to keep
// loads in flight; R9's global-B on the serial chain was fatal):
//  - __launch_bounds__(512,4): 128-VGPR budget -> deep load pipelining.
//  - MFMA 32x32x16 (2x K-bytes per FLOP better than 16x16x32). Block tile
//    M=64 sites (4h x 16w), 8 waves = 2 m-tiles x 4 n-tiles; per wave 36
//    iters: 1 ds_read_b128 (A) + 1 contiguous global dwordx4 (B) + 1 MFMA,
//    16-deep f32 acc.
//  - W repacked [nt][ks][lane][8]: each wave's B-fragment is one contiguous
//    1 KB line (coalesced, L1-friendly).
//  - Z-row XOR swizzle (byte ^= pw<<4 on write AND read): 8 distinct bank
//    bases for the b32 write pattern (R8/R9 had 4), balanced b128 reads.
//  - 4h tile: x loads 6 rows / 4 h-sites (was 4/2) -> ~25% less x HBM.
// LDS 64 rows x 600 ushort = 76.8 KB -> 2 blocks/CU (16 waves/CU).
// MFMA layouts: A row=lane&31, k=(lane>>5)*8+e; B col=lane&31 same k;
// C/D col(lane&31)=co, row=(reg&3)+8*(reg>>2)+4*(lane>>5)=m (m74/m101).

#define B_   8
#define C_   64
#define H_   128
#define W_   128
#define CO_  128
#define K_   576    // C_*9 = 36*16
#define MT   64     // sites per block (4h x 16w)
#define SROW 600    // LDS row stride in elements (1200 B)

typedef __attribute__((ext_vector_type(8)))  short  short8;
typedef __attribute__((ext_vector_type(8)))  __bf16 bf16x8;
typedef __attribute__((ext_vector_type(16))) float  f32x16;
typedef __attribute__((ext_vector_type(2)))  float  f32x2;

__device__ __forceinline__ void cswap2(f32x2 &a, f32x2 &b) {
    f32x2 lo = __builtin_elementwise_min(a, b);
    f32x2 hi = __builtin_elementwise_max(a, b);
    a = lo; b = hi;
}

__device__ __forceinline__ ushort f2bf(float f) {
    union { float f; unsigned u; } v; v.f = f;
    unsigned r = v.u + 0x7fffu + ((v.u >> 16) & 1u);  // RNE
    return (ushort)(r >> 16);
}

__device__ __forceinline__ unsigned pack2bf(float lo, float hi) {
    union { __hip_bfloat162 h; unsigned u; } cv;
    cv.h = __float22bfloat162_rn(make_float2(lo, hi));  // x->low word
    return cv.u;
}

// Repack W[co][k] f32 -> Wb[((nt*36+ks)*64+lane)*8+e] bf16 where
// co = nt*32+(lane&31), k = ks*16+(lane>>5)*8+e. One contiguous 1 KB line
// per (nt,ks) = exactly one wave-fragment.
__global__ __launch_bounds__(256) void conv_W_bf16(const float* __restrict__ Wg,
                                                   ushort* __restrict__ Wb) {
    int i = blockIdx.x * 256 + threadIdx.x;
    if (i >= CO_ * K_) return;
    const int e    = i & 7;
    const int lane = (i >> 3) & 63;
    const int t    = i >> 9;            // nt*36 + ks
    const int nt   = t / 36;
    const int ks   = t - nt * 36;
    const int co   = nt * 32 + (lane & 31);
    const int k    = ks * 16 + (lane >> 5) * 8 + e;
    Wb[i] = f2bf(Wg[co * K_ + k]);
}

__global__ __launch_bounds__(512, 4) void sconv_mfma(
    const float* __restrict__ x,
    const float* __restrict__ Coef,
    const ushort* __restrict__ Wb,     // bf16 bits, repacked (see above)
    const float* __restrict__ bias,
    float* __restrict__ out)
{
    __shared__ __align__(16) ushort Zl[MT * SROW];   // 76800 B -> 2 blocks/CU

    const int tid = threadIdx.x;
    const int bx  = blockIdx.x;
    const int wq  = bx & 7;            // 16-wide w slice
    const int hq  = (bx >> 3) & 31;    // h quad index
    const int b   = bx >> 8;
    const int w0  = wq * 16;
    const int h0  = hq * 4;

    // ---- Phase A: z for 64 c x (4h x 16w); 2w x 4h sites per thread ----
    {
        const int c  = tid >> 3;               // 64 channels
        const int pw = tid & 7;                // 8 w-pairs
        const int w  = w0 + pw * 2;
        const float* xb = x + ((size_t)(b * C_ + c)) * (H_ * W_);

        // 6 rows x 4 cols of padded input (covers 2w x 4h sites' patches)
        float r[6][4];
        const bool interior = (h0 >= 4) && (h0 <= 120) && (w0 >= 16) && (w0 <= 96);
        if (interior) {                        // block-uniform: scalar branch
            const float* bp = xb + (h0 - 1) * W_ + (w - 1);
            #pragma unroll
            for (int dy = 0; dy < 6; ++dy) {
                float4 v; __builtin_memcpy(&v, bp + dy * W_, 16);  // dwordx4 @4B align
                r[dy][0] = v.x; r[dy][1] = v.y; r[dy][2] = v.z; r[dy][3] = v.w;
            }
        } else {
            // branch-free clamped loads + selects (no per-lane divergence)
            const int wm = w - 1;
            const int wc = min(max(wm, 0), W_ - 4);
            const int s  = wm - wc;            // -1 (left pad), 0, +1 (right pad)
            #pragma unroll
            for (int dy = 0; dy < 6; ++dy) {
                const int hy  = h0 + dy - 1;
                const bool hok = (unsigned)hy < (unsigned)H_;
                const int hc  = min(max(hy, 0), H_ - 1);
                float4 v; __builtin_memcpy(&v, xb + hc * W_ + wc, 16);
                const float rr0 = (s < 0) ? 0.f : ((s > 0) ? v.y : v.x);
                const float rr1 = (s < 0) ? v.x : ((s > 0) ? v.z : v.y);
                const float rr2 = (s < 0) ? v.y : ((s > 0) ? v.w : v.z);
                const float rr3 = (s < 0) ? v.z : ((s > 0) ? 0.f : v.w);
                r[dy][0] = hok ? rr0 : 0.f;
                r[dy][1] = hok ? rr1 : 0.f;
                r[dy][2] = hok ? rr2 : 0.f;
                r[dy][3] = hok ? rr3 : 0.f;
            }
        }

        const int k0 = c * 9;
        const int sw = pw << 4;                // = ((row>>1)&7)<<4 for both rows
        #pragma unroll
        for (int hl = 0; hl < 4; ++hl) {       // adjacent h-sites share rows
            f32x2 p2[9];
            #pragma unroll
            for (int dy = 0; dy < 3; ++dy)
                #pragma unroll
                for (int dx = 0; dx < 3; ++dx)
                    p2[dy * 3 + dx] = (f32x2){ r[hl + dy][dx], r[hl + dy][dx + 1] };

            // y_i for i in {0,1,2,3,5,6,7,8}; Coef via uniform (scalar) loads
            f32x2 v2[8];
            #pragma unroll
            for (int ii = 0; ii < 8; ++ii) {
                const int i = ii + (ii >> 2);
                f32x2 acc = p2[0] * Coef[i * 9];
                #pragma unroll
                for (int j = 1; j < 9; ++j) acc += p2[j] * Coef[i * 9 + j];
                v2[ii] = acc;
            }

            // Batcher odd-even mergesort, 8 elems, ascending (19 comparators)
            cswap2(v2[0],v2[1]); cswap2(v2[2],v2[3]); cswap2(v2[4],v2[5]); cswap2(v2[6],v2[7]);
            cswap2(v2[0],v2[2]); cswap2(v2[1],v2[3]); cswap2(v2[4],v2[6]); cswap2(v2[5],v2[7]);
            cswap2(v2[1],v2[2]); cswap2(v2[5],v2[6]);
            cswap2(v2[0],v2[4]); cswap2(v2[1],v2[5]); cswap2(v2[2],v2[6]); cswap2(v2[3],v2[7]);
            cswap2(v2[2],v2[4]); cswap2(v2[3],v2[5]);
            cswap2(v2[1],v2[2]); cswap2(v2[3],v2[4]); cswap2(v2[5],v2[6]);

            f32x2 z2[9] = { v2[0], v2[1], v2[2], v2[3], p2[4],
                            v2[4], v2[5], v2[6], v2[7] };

            // Z rows m = hl*16 + (pw*2, pw*2+1); byte offsets XOR sw
            char* zb0 = (char*)Zl + (size_t)(hl * 16 + pw * 2) * (SROW * 2);
            char* zb1 = zb0 + SROW * 2;
            if ((k0 & 1) == 0) {                    // pairs k0.., single at k0+8
                #pragma unroll
                for (int q = 0; q < 4; ++q) {
                    *(unsigned*)(zb0 + (((k0 + 2*q) * 2) ^ sw)) = pack2bf(z2[2*q][0], z2[2*q+1][0]);
                    *(unsigned*)(zb1 + (((k0 + 2*q) * 2) ^ sw)) = pack2bf(z2[2*q][1], z2[2*q+1][1]);
                }
                *(ushort*)(zb0 + (((k0 + 8) * 2) ^ sw)) = f2bf(z2[8][0]);
                *(ushort*)(zb1 + (((k0 + 8) * 2) ^ sw)) = f2bf(z2[8][1]);
            } else {                                // single at k0, pairs k0+1..
                *(ushort*)(zb0 + ((k0 * 2) ^ sw)) = f2bf(z2[0][0]);
                *(ushort*)(zb1 + ((k0 * 2) ^ sw)) = f2bf(z2[0][1]);
                #pragma unroll
                for (int q = 0; q < 4; ++q) {
                    *(unsigned*)(zb0 + (((k0 + 1 + 2*q) * 2) ^ sw)) = pack2bf(z2[1+2*q][0], z2[2+2*q][0]);
                    *(unsigned*)(zb1 + (((k0 + 1 + 2*q) * 2) ^ sw)) = pack2bf(z2[1+2*q][1], z2[2+2*q][1]);
                }
            }
        }
    }
    __syncthreads();

    // ---- Phase B: 32x32x16 MFMA GEMM  out[m, n=co] = sum_k Z[m,k]W^T[n,k]
    const int wave = tid >> 6;
    const int lane = tid & 63;
    const int mt   = wave >> 2;        // m-tile: Z rows mt*32..+31
    const int nt   = wave & 3;         // n-tile: co nt*32..+31
    const int r31  = lane & 31;
    const int u    = lane >> 5;

    const int arow = mt * 32 + r31;
    const char* abase = (const char*)Zl + (size_t)arow * (SROW * 2);
    const int aswz = ((arow >> 1) & 7) << 4;
    const ushort* bptr = Wb + ((size_t)(nt * 36) * 64 + lane) * 8;

    f32x16 acc = {};

    #pragma unroll
    for (int ks = 0; ks < 36; ++ks) {
        bf16x8 a  = *(const bf16x8*)(abase + ((ks * 32 + u * 16) ^ aswz));
        bf16x8 bb = __builtin_bit_cast(bf16x8, *(const short8*)(bptr + ks * 512));
        acc = __builtin_amdgcn_mfma_f32_32x32x16_bf16(a, bb, acc, 0, 0, 0);
    }

    // ---- Epilogue: D col=lane&31 -> co-local; row=(reg&3)+8*(reg>>2)+4*u
    const int co = nt * 32 + r31;
    const float bv = bias[co];
    float* obase = out + (((size_t)(b * CO_ + co)) * H_ + h0 + mt * 2) * W_ + w0;
    #pragma unroll
    for (int qq = 0; qq < 4; ++qq) {
        const int roff = qq * 8 + u * 4;       // m-local base, multiple of 4
        const int hl   = roff >> 4;            // 0 or 1 within this m-tile
        const int wl   = roff & 15;            // 0,4,8,12
        float4 vv = make_float4(acc[qq*4+0] + bv, acc[qq*4+1] + bv,
                                acc[qq*4+2] + bv, acc[qq*4+3] + bv);
        *(float4*)(obase + hl * W_ + wl) = vv;
    }
}

// ---- fp32 fallback (round-1 kernel, direct W layout) if ws is too small ----
#define WT 16
__device__ __forceinline__ void cswap(float &a, float &b) {
    float lo = fminf(a, b);
    float hi = fmaxf(a, b);
    a = lo; b = hi;
}
__global__ __launch_bounds__(256) void sconv_fp32(
    const float* __restrict__ x, const float* __restrict__ Coef,
    const float* __restrict__ Wg, const float* __restrict__ bias,
    float* __restrict__ out)
{
    __shared__ float Cf[81];
    __shared__ float Zl[C_ * 9 * WT];
    const int tid = threadIdx.x;
    const int bx  = blockIdx.x;
    const int wt  = bx & 7;
    const int h   = (bx >> 3) & 127;
    const int b   = bx >> 10;
    const int w0  = wt * WT;
    if (tid < 81) Cf[tid] = Coef[tid];
    __syncthreads();
    for (int task = tid; task < C_ * WT; task += 256) {
        const int c = task >> 4, wl = task & 15, w = w0 + wl;
        const float* xb = x + (b * C_ + c) * H_ * W_;
        float p[9];
        #pragma unroll
        for (int dy = 0; dy < 3; ++dy) {
            const int hy = h + dy - 1; const bool hin = (unsigned)hy < (unsigned)H_;
            #pragma unroll
            for (int dx = 0; dx < 3; ++dx) {
                const int wx = w + dx - 1; const bool win = (unsigned)wx < (unsigned)W_;
                p[dy * 3 + dx] = (hin && win) ? xb[hy * W_ + wx] : 0.0f;
            }
        }
        float v[8];
        #pragma unroll
        for (int ii = 0; ii < 8; ++ii) {
            const int i = ii + (ii >> 2);
            float acc = 0.0f;
            #pragma unroll
            for (int j = 0; j < 9; ++j) acc = fmaf(Cf[i * 9 + j], p[j], acc);
            v[ii] = acc;
        }
        cswap(v[0], v[1]); cswap(v[2], v[3]); cswap(v[4], v[5]); cswap(v[6], v[7]);
        cswap(v[0], v[2]); cswap(v[1], v[3]); cswap(v[4], v[6]); cswap(v[5], v[7]);
        cswap(v[1], v[2]); cswap(v[5], v[6]);
        cswap(v[0], v[4]); cswap(v[1], v[5]); cswap(v[2], v[6]); cswap(v[3], v[7]);
        cswap(v[2], v[4]); cswap(v[3], v[5]);
        cswap(v[1], v[2]); cswap(v[3], v[4]); cswap(v[5], v[6]);
        const int base = c * 9 * WT + wl;
        Zl[base + 0*WT]=v[0]; Zl[base + 1*WT]=v[1]; Zl[base + 2*WT]=v[2]; Zl[base + 3*WT]=v[3];
        Zl[base + 4*WT]=p[4];
        Zl[base + 5*WT]=v[4]; Zl[base + 6*WT]=v[5]; Zl[base + 7*WT]=v[6]; Zl[base + 8*WT]=v[7];
    }
    __syncthreads();
    const int co = tid >> 1, w0l = (tid & 1) * 8;
    float acc[8];
    #pragma unroll
    for (int i = 0; i < 8; ++i) acc[i] = 0.0f;
    for (int c = 0; c < C_; ++c) {
        #pragma unroll
        for (int t = 0; t < 9; ++t) {
            const float wv = Wg[(co * C_ + c) * 9 + t];
            const float* zp = &Zl[(c * 9 + t) * WT + w0l];
            const float4 za = *(const float4*)zp;
            const float4 zb = *(const float4*)(zp + 4);
            acc[0]=fmaf(za.x,wv,acc[0]); acc[1]=fmaf(za.y,wv,acc[1]);
            acc[2]=fmaf(za.z,wv,acc[2]); acc[3]=fmaf(za.w,wv,acc[3]);
            acc[4]=fmaf(zb.x,wv,acc[4]); acc[5]=fmaf(zb.y,wv,acc[5]);
            acc[6]=fmaf(zb.z,wv,acc[6]); acc[7]=fmaf(zb.w,wv,acc[7]);
        }
    }
    const float bv = bias[co];
    float* op = out + ((b * CO_ + co) * H_ + h) * W_ + w0 + w0l;
    *(float4*)(op)     = make_float4(acc[0]+bv, acc[1]+bv, acc[2]+bv, acc[3]+bv);
    *(float4*)(op + 4) = make_float4(acc[4]+bv, acc[5]+bv, acc[6]+bv, acc[7]+bv);
}

extern "C" void kernel_launch(void* const* d_in, const int* in_sizes, int n_in,
                              void* d_out, int out_size, void* d_ws, size_t ws_size,
                              hipStream_t stream) {
    const float* x    = (const float*)d_in[0];
    const float* Coef = (const float*)d_in[1];
    const float* Wg   = (const float*)d_in[2];
    const float* bias = (const float*)d_in[3];
    float* out = (float*)d_out;

    const size_t need = (size_t)CO_ * K_ * sizeof(ushort);   // 147456 B
    if (ws_size >= need) {
        ushort* Wb = (ushort*)d_ws;
        conv_W_bf16<<<(CO_ * K_ + 255) / 256, 256, 0, stream>>>(Wg, Wb);
        sconv_mfma<<<B_ * (H_ / 4) * (W_ / 16), 512, 0, stream>>>(x, Coef, Wb, bias, out);
    } else {
        sconv_fp32<<<B_ * H_ * 8, 256, 0, stream>>>(x, Coef, Wg, bias, out);
    }
}

// Round 4
// 137.747 us; speedup vs baseline: 1.6492x; 1.0100x over previous
//
#include <hip/hip_runtime.h>
#include <hip/hip_bf16.h>

// SConv: x(8,64,128,128) f32, Coefficient(9,9), W(128,64,3,3), b(128)
// out[b,co,h,w] = sum_{c,t} z[b,c,h,w][t] * W[co,c,t] + b[co]
// z = [sorted8(y[noncenter])[0:4], center, sorted8[4:8]],
// y_i = sum_j Coefficient[i,j] * patch_j (3x3 neighborhood, zero pad 1).
//
// Round 11 (vs R10 64.4 us kernel: still latency-exposed — VGPR only 52/128,
// compiler didn't pipeline Phase-B loads; Phase-A parity branch diverges):
//  - Phase B: explicit register prefetch queues, B depth 8 (global/L2,
//    ~300cy) issued BEFORE __syncthreads (independent of Phase A -> hides
//    under barrier), A depth 4 (ds_read ~120cy). Static queue indices +
//    full unroll (rule #20: no runtime-indexed vector arrays).
//  - A-fragment addresses: 4 per-thread swizzled base pointers + immediate
//    offsets (ks>>2)*128 -> zero per-iteration address VALU.
//  - Phase A: c = wave + 8*j mapping makes k0=9c parity WAVE-UNIFORM ->
//    store-parity branch scalarizes (was: both paths exec-masked in every
//    wave). Same coverage, same 128-B coalescing.
// LDS 64 rows x 600 ushort = 76.8 KB -> 2 blocks/CU. MFMA 32x32x16.
// Layouts: A row=lane&31, k=(lane>>5)*8+e; C/D col=lane&31=co,
// row=(reg&3)+8*(reg>>2)+4*(lane>>5) (m74/m101).

#define B_   8
#define C_   64
#define H_   128
#define W_   128
#define CO_  128
#define K_   576    // C_*9 = 36*16
#define MT   64     // sites per block (4h x 16w)
#define SROW 600    // LDS row stride in elements (1200 B)

typedef __attribute__((ext_vector_type(8)))  short  short8;
typedef __attribute__((ext_vector_type(8)))  __bf16 bf16x8;
typedef __attribute__((ext_vector_type(16))) float  f32x16;
typedef __attribute__((ext_vector_type(2)))  float  f32x2;

__device__ __forceinline__ void cswap2(f32x2 &a, f32x2 &b) {
    f32x2 lo = __builtin_elementwise_min(a, b);
    f32x2 hi = __builtin_elementwise_max(a, b);
    a = lo; b = hi;
}

__device__ __forceinline__ ushort f2bf(float f) {
    union { float f; unsigned u; } v; v.f = f;
    unsigned r = v.u + 0x7fffu + ((v.u >> 16) & 1u);  // RNE
    return (ushort)(r >> 16);
}

__device__ __forceinline__ unsigned pack2bf(float lo, float hi) {
    union { __hip_bfloat162 h; unsigned u; } cv;
    cv.h = __float22bfloat162_rn(make_float2(lo, hi));  // x->low word
    return cv.u;
}

// Repack W[co][k] f32 -> Wb[((nt*36+ks)*64+lane)*8+e] bf16 where
// co = nt*32+(lane&31), k = ks*16+(lane>>5)*8+e. One contiguous 1 KB line
// per (nt,ks) = exactly one wave-fragment.
__global__ __launch_bounds__(256) void conv_W_bf16(const float* __restrict__ Wg,
                                                   ushort* __restrict__ Wb) {
    int i = blockIdx.x * 256 + threadIdx.x;
    if (i >= CO_ * K_) return;
    const int e    = i & 7;
    const int lane = (i >> 3) & 63;
    const int t    = i >> 9;            // nt*36 + ks
    const int nt   = t / 36;
    const int ks   = t - nt * 36;
    const int co   = nt * 32 + (lane & 31);
    const int k    = ks * 16 + (lane >> 5) * 8 + e;
    Wb[i] = f2bf(Wg[co * K_ + k]);
}

__global__ __launch_bounds__(512, 4) void sconv_mfma(
    const float* __restrict__ x,
    const float* __restrict__ Coef,
    const ushort* __restrict__ Wb,     // bf16 bits, repacked (see above)
    const float* __restrict__ bias,
    float* __restrict__ out)
{
    __shared__ __align__(16) ushort Zl[MT * SROW];   // 76800 B -> 2 blocks/CU

    const int tid = threadIdx.x;
    const int bx  = blockIdx.x;
    const int wq  = bx & 7;            // 16-wide w slice
    const int hq  = (bx >> 3) & 31;    // h quad index
    const int b   = bx >> 8;
    const int w0  = wq * 16;
    const int h0  = hq * 4;

    // Phase-B addressing hoisted: B prefetch is issued BEFORE the barrier.
    const int wave = tid >> 6;
    const int lane = tid & 63;
    const int mt   = wave >> 2;        // m-tile: Z rows mt*32..+31
    const int nt   = wave & 3;         // n-tile: co nt*32..+31
    const int r31  = lane & 31;
    const int u    = lane >> 5;
    const ushort* bptr = Wb + ((size_t)(nt * 36) * 64 + lane) * 8;

    // ---- Phase A: z for 64 c x (4h x 16w); 2w x 4h sites per thread ----
    {
        // c = wave + 8*j: all c in a wave share parity(9c) -> uniform branch
        const int j  = (tid >> 3) & 7;
        const int c  = wave + 8 * j;
        const int pw = tid & 7;                // 8 w-pairs
        const int w  = w0 + pw * 2;
        const float* xb = x + ((size_t)(b * C_ + c)) * (H_ * W_);

        // 6 rows x 4 cols of padded input (covers 2w x 4h sites' patches)
        float r[6][4];
        const bool interior = (h0 >= 4) && (h0 <= 120) && (w0 >= 16) && (w0 <= 96);
        if (interior) {                        // block-uniform: scalar branch
            const float* bp = xb + (h0 - 1) * W_ + (w - 1);
            #pragma unroll
            for (int dy = 0; dy < 6; ++dy) {
                float4 v; __builtin_memcpy(&v, bp + dy * W_, 16);  // dwordx4 @4B align
                r[dy][0] = v.x; r[dy][1] = v.y; r[dy][2] = v.z; r[dy][3] = v.w;
            }
        } else {
            // branch-free clamped loads + selects (no per-lane divergence)
            const int wm = w - 1;
            const int wc = min(max(wm, 0), W_ - 4);
            const int s  = wm - wc;            // -1 (left pad), 0, +1 (right pad)
            #pragma unroll
            for (int dy = 0; dy < 6; ++dy) {
                const int hy  = h0 + dy - 1;
                const bool hok = (unsigned)hy < (unsigned)H_;
                const int hc  = min(max(hy, 0), H_ - 1);
                float4 v; __builtin_memcpy(&v, xb + hc * W_ + wc, 16);
                const float rr0 = (s < 0) ? 0.f : ((s > 0) ? v.y : v.x);
                const float rr1 = (s < 0) ? v.x : ((s > 0) ? v.z : v.y);
                const float rr2 = (s < 0) ? v.y : ((s > 0) ? v.w : v.z);
                const float rr3 = (s < 0) ? v.z : ((s > 0) ? 0.f : v.w);
                r[dy][0] = hok ? rr0 : 0.f;
                r[dy][1] = hok ? rr1 : 0.f;
                r[dy][2] = hok ? rr2 : 0.f;
                r[dy][3] = hok ? rr3 : 0.f;
            }
        }

        const int k0 = c * 9;
        const int sw = pw << 4;                // = ((row>>1)&7)<<4 for both rows
        #pragma unroll
        for (int hl = 0; hl < 4; ++hl) {       // adjacent h-sites share rows
            f32x2 p2[9];
            #pragma unroll
            for (int dy = 0; dy < 3; ++dy)
                #pragma unroll
                for (int dx = 0; dx < 3; ++dx)
                    p2[dy * 3 + dx] = (f32x2){ r[hl + dy][dx], r[hl + dy][dx + 1] };

            // y_i for i in {0,1,2,3,5,6,7,8}; Coef via uniform (scalar) loads
            f32x2 v2[8];
            #pragma unroll
            for (int ii = 0; ii < 8; ++ii) {
                const int i = ii + (ii >> 2);
                f32x2 acc = p2[0] * Coef[i * 9];
                #pragma unroll
                for (int jj = 1; jj < 9; ++jj) acc += p2[jj] * Coef[i * 9 + jj];
                v2[ii] = acc;
            }

            // Batcher odd-even mergesort, 8 elems, ascending (19 comparators)
            cswap2(v2[0],v2[1]); cswap2(v2[2],v2[3]); cswap2(v2[4],v2[5]); cswap2(v2[6],v2[7]);
            cswap2(v2[0],v2[2]); cswap2(v2[1],v2[3]); cswap2(v2[4],v2[6]); cswap2(v2[5],v2[7]);
            cswap2(v2[1],v2[2]); cswap2(v2[5],v2[6]);
            cswap2(v2[0],v2[4]); cswap2(v2[1],v2[5]); cswap2(v2[2],v2[6]); cswap2(v2[3],v2[7]);
            cswap2(v2[2],v2[4]); cswap2(v2[3],v2[5]);
            cswap2(v2[1],v2[2]); cswap2(v2[3],v2[4]); cswap2(v2[5],v2[6]);

            f32x2 z2[9] = { v2[0], v2[1], v2[2], v2[3], p2[4],
                            v2[4], v2[5], v2[6], v2[7] };

            // Z rows m = hl*16 + (pw*2, pw*2+1); byte offsets XOR sw
            char* zb0 = (char*)Zl + (size_t)(hl * 16 + pw * 2) * (SROW * 2);
            char* zb1 = zb0 + SROW * 2;
            if ((k0 & 1) == 0) {                    // wave-uniform branch
                #pragma unroll
                for (int q = 0; q < 4; ++q) {
                    *(unsigned*)(zb0 + (((k0 + 2*q) * 2) ^ sw)) = pack2bf(z2[2*q][0], z2[2*q+1][0]);
                    *(unsigned*)(zb1 + (((k0 + 2*q) * 2) ^ sw)) = pack2bf(z2[2*q][1], z2[2*q+1][1]);
                }
                *(ushort*)(zb0 + (((k0 + 8) * 2) ^ sw)) = f2bf(z2[8][0]);
                *(ushort*)(zb1 + (((k0 + 8) * 2) ^ sw)) = f2bf(z2[8][1]);
            } else {                                // single at k0, pairs k0+1..
                *(ushort*)(zb0 + ((k0 * 2) ^ sw)) = f2bf(z2[0][0]);
                *(ushort*)(zb1 + ((k0 * 2) ^ sw)) = f2bf(z2[0][1]);
                #pragma unroll
                for (int q = 0; q < 4; ++q) {
                    *(unsigned*)(zb0 + (((k0 + 1 + 2*q) * 2) ^ sw)) = pack2bf(z2[1+2*q][0], z2[2+2*q][0]);
                    *(unsigned*)(zb1 + (((k0 + 1 + 2*q) * 2) ^ sw)) = pack2bf(z2[1+2*q][1], z2[2+2*q][1]);
                }
            }
        }
    }

    // ---- B prefetch (independent of Phase A): hide L2 latency under barrier
    short8 bq[8];
    #pragma unroll
    for (int i = 0; i < 8; ++i) bq[i] = *(const short8*)(bptr + i * 512);

    __syncthreads();

    // ---- Phase B: 32x32x16 MFMA GEMM  out[m, n=co] = sum_k Z[m,k]W^T[n,k]
    const int arow = mt * 32 + r31;
    const char* abase = (const char*)Zl + (size_t)arow * (SROW * 2);
    const int aswz = ((arow >> 1) & 7) << 4;
    // 4 swizzled base pointers; all 36 ds_reads use immediate offsets.
    const char* pj[4];
    #pragma unroll
    for (int j = 0; j < 4; ++j)
        pj[j] = abase + (((j * 32) | (u * 16)) ^ aswz);

    bf16x8 aq[4];
    #pragma unroll
    for (int i = 0; i < 4; ++i)
        aq[i] = *(const bf16x8*)(pj[i & 3] + (i >> 2) * 128);

    f32x16 acc = {};

    #pragma unroll
    for (int ks = 0; ks < 36; ++ks) {
        bf16x8 a  = aq[ks & 3];
        short8 bb = bq[ks & 7];
        if (ks + 4 < 36)
            aq[ks & 3] = *(const bf16x8*)(pj[(ks + 4) & 3] + ((ks + 4) >> 2) * 128);
        if (ks + 8 < 36)
            bq[ks & 7] = *(const short8*)(bptr + (ks + 8) * 512);
        acc = __builtin_amdgcn_mfma_f32_32x32x16_bf16(a, __builtin_bit_cast(bf16x8, bb), acc, 0, 0, 0);
    }

    // ---- Epilogue: D col=lane&31 -> co-local; row=(reg&3)+8*(reg>>2)+4*u
    const int co = nt * 32 + r31;
    const float bv = bias[co];
    float* obase = out + (((size_t)(b * CO_ + co)) * H_ + h0 + mt * 2) * W_ + w0;
    #pragma unroll
    for (int qq = 0; qq < 4; ++qq) {
        const int roff = qq * 8 + u * 4;       // m-local base, multiple of 4
        const int hl   = roff >> 4;            // 0 or 1 within this m-tile
        const int wl   = roff & 15;            // 0,4,8,12
        float4 vv = make_float4(acc[qq*4+0] + bv, acc[qq*4+1] + bv,
                                acc[qq*4+2] + bv, acc[qq*4+3] + bv);
        *(float4*)(obase + hl * W_ + wl) = vv;
    }
}

// ---- fp32 fallback (round-1 kernel, direct W layout) if ws is too small ----
#define WT 16
__device__ __forceinline__ void cswap(float &a, float &b) {
    float lo = fminf(a, b);
    float hi = fmaxf(a, b);
    a = lo; b = hi;
}
__global__ __launch_bounds__(256) void sconv_fp32(
    const float* __restrict__ x, const float* __restrict__ Coef,
    const float* __restrict__ Wg, const float* __restrict__ bias,
    float* __restrict__ out)
{
    __shared__ float Cf[81];
    __shared__ float Zl[C_ * 9 * WT];
    const int tid = threadIdx.x;
    const int bx  = blockIdx.x;
    const int wt  = bx & 7;
    const int h   = (bx >> 3) & 127;
    const int b   = bx >> 10;
    const int w0  = wt * WT;
    if (tid < 81) Cf[tid] = Coef[tid];
    __syncthreads();
    for (int task = tid; task < C_ * WT; task += 256) {
        const int c = task >> 4, wl = task & 15, w = w0 + wl;
        const float* xb = x + (b * C_ + c) * H_ * W_;
        float p[9];
        #pragma unroll
        for (int dy = 0; dy < 3; ++dy) {
            const int hy = h + dy - 1; const bool hin = (unsigned)hy < (unsigned)H_;
            #pragma unroll
            for (int dx = 0; dx < 3; ++dx) {
                const int wx = w + dx - 1; const bool win = (unsigned)wx < (unsigned)W_;
                p[dy * 3 + dx] = (hin && win) ? xb[hy * W_ + wx] : 0.0f;
            }
        }
        float v[8];
        #pragma unroll
        for (int ii = 0; ii < 8; ++ii) {
            const int i = ii + (ii >> 2);
            float acc = 0.0f;
            #pragma unroll
            for (int j = 0; j < 9; ++j) acc = fmaf(Cf[i * 9 + j], p[j], acc);
            v[ii] = acc;
        }
        cswap(v[0], v[1]); cswap(v[2], v[3]); cswap(v[4], v[5]); cswap(v[6], v[7]);
        cswap(v[0], v[2]); cswap(v[1], v[3]); cswap(v[4], v[6]); cswap(v[5], v[7]);
        cswap(v[1], v[2]); cswap(v[5], v[6]);
        cswap(v[0], v[4]); cswap(v[1], v[5]); cswap(v[2], v[6]); cswap(v[3], v[7]);
        cswap(v[2], v[4]); cswap(v[3], v[5]);
        cswap(v[1], v[2]); cswap(v[3], v[4]); cswap(v[5], v[6]);
        const int base = c * 9 * WT + wl;
        Zl[base + 0*WT]=v[0]; Zl[base + 1*WT]=v[1]; Zl[base + 2*WT]=v[2]; Zl[base + 3*WT]=v[3];
        Zl[base + 4*WT]=p[4];
        Zl[base + 5*WT]=v[4]; Zl[base + 6*WT]=v[5]; Zl[base + 7*WT]=v[6]; Zl[base + 8*WT]=v[7];
    }
    __syncthreads();
    const int co = tid >> 1, w0l = (tid & 1) * 8;
    float acc[8];
    #pragma unroll
    for (int i = 0; i < 8; ++i) acc[i] = 0.0f;
    for (int c = 0; c < C_; ++c) {
        #pragma unroll
        for (int t = 0; t < 9; ++t) {
            const float wv = Wg[(co * C_ + c) * 9 + t];
            const float* zp = &Zl[(c * 9 + t) * WT + w0l];
            const float4 za = *(const float4*)zp;
            const float4 zb = *(const float4*)(zp + 4);
            acc[0]=fmaf(za.x,wv,acc[0]); acc[1]=fmaf(za.y,wv,acc[1]);
            acc[2]=fmaf(za.z,wv,acc[2]); acc[3]=fmaf(za.w,wv,acc[3]);
            acc[4]=fmaf(zb.x,wv,acc[4]); acc[5]=fmaf(zb.y,wv,acc[5]);
            acc[6]=fmaf(zb.z,wv,acc[6]); acc[7]=fmaf(zb.w,wv,acc[7]);
        }
    }
    const float bv = bias[co];
    float* op = out + ((b * CO_ + co) * H_ + h) * W_ + w0 + w0l;
    *(float4*)(op)     = make_float4(acc[0]+bv, acc[1]+bv, acc[2]+bv, acc[3]+bv);
    *(float4*)(op + 4) = make_float4(acc[4]+bv, acc[5]+bv, acc[6]+bv, acc[7]+bv);
}

extern "C" void kernel_launch(void* const* d_in, const int* in_sizes, int n_in,
                              void* d_out, int out_size, void* d_ws, size_t ws_size,
                              hipStream_t stream) {
    const float* x    = (const float*)d_in[0];
    const float* Coef = (const float*)d_in[1];
    const float* Wg   = (const float*)d_in[2];
    const float* bias = (const float*)d_in[3];
    float* out = (float*)d_out;

    const size_t need = (size_t)CO_ * K_ * sizeof(ushort);   // 147456 B
    if (ws_size >= need) {
        ushort* Wb = (ushort*)d_ws;
        conv_W_bf16<<<(CO_ * K_ + 255) / 256, 256, 0, stream>>>(Wg, Wb);
        sconv_mfma<<<B_ * (H_ / 4) * (W_ / 16), 512, 0, stream>>>(x, Coef, Wb, bias, out);
    } else {
        sconv_fp32<<<B_ * H_ * 8, 256, 0, stream>>>(x, Coef, Wg, bias, out);
    }
}